// Round 4
// baseline (317.938 us; speedup 1.0000x reference)
//
#include <hip/hip_runtime.h>
#include <hip/hip_bf16.h>

#define B_   32
#define T_   32
#define E_   32
#define SD   64
#define AD   32
#define HID  1024
#define EMB  1536
#define K2   3072   // 2*EMB

// block ranges within the fused kernel
#define NB_AE   (6 * B_)                 // 192  (aemb chunks; chunk0 also tau)
#define NB_SH   B_                       // 32   (state_h)
#define NB_B1   ((EMB / 64) * B_)        // 768  (big GEMM 1)
#define NB_SF   ((EMB / 256) * B_)       // 192  (state_feat)
#define NB_K2   ((EMB / 64) * B_)        // 768  (big GEMM 2)
#define OFF_SH  NB_AE                    // 192
#define OFF_B1  (NB_AE + NB_SH)          // 224
#define OFF_SF  (OFF_B1 + NB_B1)         // 992
#define OFF_K2  (OFF_SF + NB_SF)         // 1184
#define NBLK    (OFF_K2 + NB_K2)         // 1952

typedef __attribute__((ext_vector_type(8))) short  bf16x8;
typedef __attribute__((ext_vector_type(8))) short  s16x8;
typedef __attribute__((ext_vector_type(4))) float  f32x4;

// round-to-nearest-even f32 -> bf16 bits
__device__ __forceinline__ unsigned short f2bf(float f) {
    unsigned u = __builtin_bit_cast(unsigned, f);
    u = u + 0x7fffu + ((u >> 16) & 1u);
    return (unsigned short)(u >> 16);
}

__device__ __forceinline__ float swishf(float y) {
    return y / (1.f + expf(-y));
}

// producer: all threads done storing -> __syncthreads() -> tid0 signals
__device__ __forceinline__ void gate_signal(int* g) {
    __syncthreads();
    if (threadIdx.x == 0)
        __hip_atomic_fetch_add(g, 1, __ATOMIC_RELEASE, __HIP_MEMORY_SCOPE_AGENT);
}

// consumer: tid0 spins with acquire (agent scope invalidates stale L1/L2)
__device__ __forceinline__ void gate_wait(const int* g, int target) {
    if (threadIdx.x == 0) {
        while (__hip_atomic_load(g, __ATOMIC_ACQUIRE, __HIP_MEMORY_SCOPE_AGENT) < target)
            __builtin_amdgcn_s_sleep(8);
    }
    __syncthreads();
}

// ---------------------------------------------------------------------------
// fused kernel: prep (aemb+tau, state_h) -> big1 + state_feat -> big2,
// gated per-batch so phases overlap instead of full-device drains.
// ---------------------------------------------------------------------------
__global__ __launch_bounds__(256) void k_fused(
    const float* __restrict__ state, const float* __restrict__ actions,
    const int* __restrict__ tsteps, const int* __restrict__ cat_ids,
    const float* __restrict__ se_W1, const float* __restrict__ se_b1,
    const float* __restrict__ se_W2, const float* __restrict__ se_b2,
    const float* __restrict__ ae_W1, const float* __restrict__ ae_b1,
    const float* __restrict__ ae_W2, const float* __restrict__ ae_b2,
    const float* __restrict__ ae_W3, const float* __restrict__ ae_b3,
    int* __restrict__ gate_ae, int* __restrict__ gate_h, int* __restrict__ gate_x3,
    unsigned short* __restrict__ tau, float* __restrict__ h,
    unsigned short* __restrict__ aemb, unsigned short* __restrict__ x3,
    float* __restrict__ out) {
    __shared__ float lds[4][32][64];        // 32 KB, reused by all branches
    int bid = blockIdx.x, tid = threadIdx.x;
    int wv = tid >> 6, lane = tid & 63;

    if (bid < NB_AE) {
        // ---- aemb (b-major): b's 6 chunks adjacent; chunk 0 also does tau
        int b = bid / 6, chunk = bid % 6;
        int c = cat_ids[b];
        if (chunk == 0) {
            float t = (float)tsteps[b];
            const int half = EMB / 2;
            for (int i = tid; i < half; i += 256) {
                float div = expf((-logf(10000.0f) * (float)i) / (float)half);
                float ang = t * div;
                tau[b * EMB + i]        = f2bf(sinf(ang));
                tau[b * EMB + half + i] = f2bf(cosf(ang));
            }
        }
        float* sa = (float*)lds;
#pragma unroll
        for (int r = 0; r < 4; ++r)
            sa[tid + 256 * r] = actions[b * T_ * AD + tid + 256 * r];
        __syncthreads();
        int n = chunk * 256 + tid;
        const float* W = ae_W1 + (size_t)c * AD * EMB + n;
        float bv = ae_b1[c * EMB + n];
        float acc[T_];
#pragma unroll
        for (int t = 0; t < T_; ++t) acc[t] = bv;
        for (int k = 0; k < AD; ++k) {
            float w = W[(size_t)k * EMB];
#pragma unroll
            for (int t = 0; t < T_; ++t) acc[t] += sa[t * AD + k] * w;
        }
#pragma unroll
        for (int t = 0; t < T_; ++t)
            aemb[((size_t)b * T_ + t) * EMB + n] = f2bf(acc[t]);
        gate_signal(&gate_ae[b]);
        return;
    }

    if (bid < OFF_B1) {
        // ---- state_h: h = relu(state @ se_W1 + se_b1)
        int b = bid - OFF_SH;
        int c = cat_ids[b];
        float* s = (float*)lds;
        if (tid < SD) s[tid] = state[b * SD + tid];
        __syncthreads();
        const float* W = se_W1 + (size_t)c * SD * HID;
        float acc[4];
#pragma unroll
        for (int r = 0; r < 4; ++r) acc[r] = se_b1[c * HID + tid + 256 * r];
        for (int k = 0; k < SD; ++k) {
            float sv = s[k];
#pragma unroll
            for (int r = 0; r < 4; ++r)
                acc[r] += sv * W[(size_t)k * HID + tid + 256 * r];
        }
#pragma unroll
        for (int r = 0; r < 4; ++r) {
            float v = acc[r];
            h[b * HID + tid + 256 * r] = v > 0.f ? v : 0.f;
        }
        gate_signal(&gate_h[b]);
        return;
    }

    if (bid < OFF_SF) {
        // ---- big1: x3 = swish(concat(a_emb,tau) @ ae_W2 + ae_b2), bf16 out
        // slot-major bid so all blocks co-resident; 4-wave K-split + LDS reduce
        int idx = bid - OFF_B1;
        int b = idx / 24, chunk = idx % 24;
        int c = cat_ids[b];
        int cq = lane & 15, kg = lane >> 4;
        int ncol = chunk * 64 + 4 * cq;
        const float* Wb = ae_W2 + (size_t)c * K2 * EMB + ncol;

        gate_wait(&gate_ae[b], 6);

        f32x4 acc[2][4];
#pragma unroll
        for (int rf = 0; rf < 2; ++rf)
#pragma unroll
            for (int q = 0; q < 4; ++q) acc[rf][q] = (f32x4){0.f, 0.f, 0.f, 0.f};

        int kbeg = wv * 768;
        if (wv < 2) {                       // a_emb region (k 0..1535)
            const unsigned short* A0 = aemb + (size_t)b * T_ * EMB;
#pragma unroll 2
            for (int kk = 0; kk < 768; kk += 32) {
                int kb = kbeg + kk + kg * 8;
                f32x4 w[8];
#pragma unroll
                for (int j = 0; j < 8; ++j)
                    w[j] = *(const f32x4*)(Wb + (size_t)(kb + j) * EMB);
                bf16x8 bq[4];
#pragma unroll
                for (int q = 0; q < 4; ++q)
#pragma unroll
                    for (int j = 0; j < 8; ++j) bq[q][j] = (short)f2bf(w[j][q]);
                bf16x8 a0 = *(const bf16x8*)(A0 + (size_t)cq * EMB + kb);
                bf16x8 a1 = *(const bf16x8*)(A0 + (size_t)(cq + 16) * EMB + kb);
#pragma unroll
                for (int q = 0; q < 4; ++q) {
                    acc[0][q] = __builtin_amdgcn_mfma_f32_16x16x32_bf16(a0, bq[q], acc[0][q], 0, 0, 0);
                    acc[1][q] = __builtin_amdgcn_mfma_f32_16x16x32_bf16(a1, bq[q], acc[1][q], 0, 0, 0);
                }
            }
        } else {                            // tau region (k 1536..3071)
            const unsigned short* TA = tau + (size_t)b * EMB;
#pragma unroll 2
            for (int kk = 0; kk < 768; kk += 32) {
                int kb = kbeg + kk + kg * 8;
                f32x4 w[8];
#pragma unroll
                for (int j = 0; j < 8; ++j)
                    w[j] = *(const f32x4*)(Wb + (size_t)(kb + j) * EMB);
                bf16x8 bq[4];
#pragma unroll
                for (int q = 0; q < 4; ++q)
#pragma unroll
                    for (int j = 0; j < 8; ++j) bq[q][j] = (short)f2bf(w[j][q]);
                bf16x8 a = *(const bf16x8*)(TA + (kb - EMB));
#pragma unroll
                for (int q = 0; q < 4; ++q) {
                    acc[0][q] = __builtin_amdgcn_mfma_f32_16x16x32_bf16(a, bq[q], acc[0][q], 0, 0, 0);
                    acc[1][q] = __builtin_amdgcn_mfma_f32_16x16x32_bf16(a, bq[q], acc[1][q], 0, 0, 0);
                }
            }
        }
#pragma unroll
        for (int rf = 0; rf < 2; ++rf)
#pragma unroll
            for (int r = 0; r < 4; ++r) {
                int row = kg * 4 + r + 16 * rf;
                f32x4 v;
#pragma unroll
                for (int q = 0; q < 4; ++q) v[q] = acc[rf][q][r];
                *(f32x4*)&lds[wv][row][4 * cq] = v;
            }
        __syncthreads();
        int row = tid >> 3, c0 = (tid & 7) * 8;
        int gcol = chunk * 64 + c0;
        s16x8 o;
#pragma unroll
        for (int j = 0; j < 8; ++j) {
            float y = lds[0][row][c0 + j] + lds[1][row][c0 + j]
                    + lds[2][row][c0 + j] + lds[3][row][c0 + j]
                    + ae_b2[c * EMB + gcol + j];
            o[j] = (short)f2bf(swishf(y));
        }
        *(s16x8*)(x3 + ((size_t)b * T_ + row) * EMB + gcol) = o;
        gate_signal(&gate_x3[b]);
        return;
    }

    if (bid < OFF_K2) {
        // ---- state_feat: out[b,0,:] = h @ se_W2 + se_b2 (overlaps big1)
        int idx = bid - OFF_SF;
        int b = idx & 31, chunk = idx >> 5;
        int c = cat_ids[b];
        gate_wait(&gate_h[b], 1);
        int n = chunk * 256 + 4 * lane;
        const float* W = se_W2 + (size_t)c * HID * EMB + n;
        const float* hb = h + (size_t)b * HID;
        f32x4 acc = {0.f, 0.f, 0.f, 0.f};
        int ke = 256 * wv + 256;
#pragma unroll 16
        for (int k = 256 * wv; k < ke; ++k) {
            f32x4 wvv = *(const f32x4*)(W + (size_t)k * EMB);
            float hk = hb[k];
            acc += hk * wvv;
        }
        float* l = (float*)lds;
        *(f32x4*)&l[(wv * 64 + lane) * 4] = acc;
        __syncthreads();
        if (tid < 64) {
            f32x4 s = *(f32x4*)&l[tid * 4];
#pragma unroll
            for (int w = 1; w < 4; ++w) s += *(f32x4*)&l[(w * 64 + tid) * 4];
            s += *(const f32x4*)(se_b2 + (size_t)c * EMB + chunk * 256 + 4 * tid);
            *(f32x4*)(out + ((size_t)b * 33) * EMB + chunk * 256 + 4 * tid) = s;
        }
        return;
    }

    {
        // ---- big2: out[b,1+t,:] = x3 @ ae_W3 + ae_b3 (backfills big1 tail)
        int idx = bid - OFF_K2;
        int b = idx / 24, chunk = idx % 24;
        int c = cat_ids[b];
        int cq = lane & 15, kg = lane >> 4;
        int ncol = chunk * 64 + 4 * cq;
        const float* Wb = ae_W3 + (size_t)c * EMB * EMB + ncol;

        gate_wait(&gate_x3[b], 24);
        const unsigned short* A0 = x3 + (size_t)b * T_ * EMB;

        f32x4 acc[2][4];
#pragma unroll
        for (int rf = 0; rf < 2; ++rf)
#pragma unroll
            for (int q = 0; q < 4; ++q) acc[rf][q] = (f32x4){0.f, 0.f, 0.f, 0.f};

        int kbeg = wv * 384;
#pragma unroll 2
        for (int kk = 0; kk < 384; kk += 32) {
            int kb = kbeg + kk + kg * 8;
            f32x4 w[8];
#pragma unroll
            for (int j = 0; j < 8; ++j)
                w[j] = *(const f32x4*)(Wb + (size_t)(kb + j) * EMB);
            bf16x8 bq[4];
#pragma unroll
            for (int q = 0; q < 4; ++q)
#pragma unroll
                for (int j = 0; j < 8; ++j) bq[q][j] = (short)f2bf(w[j][q]);
            bf16x8 a0 = *(const bf16x8*)(A0 + (size_t)cq * EMB + kb);
            bf16x8 a1 = *(const bf16x8*)(A0 + (size_t)(cq + 16) * EMB + kb);
#pragma unroll
            for (int q = 0; q < 4; ++q) {
                acc[0][q] = __builtin_amdgcn_mfma_f32_16x16x32_bf16(a0, bq[q], acc[0][q], 0, 0, 0);
                acc[1][q] = __builtin_amdgcn_mfma_f32_16x16x32_bf16(a1, bq[q], acc[1][q], 0, 0, 0);
            }
        }
#pragma unroll
        for (int rf = 0; rf < 2; ++rf)
#pragma unroll
            for (int r = 0; r < 4; ++r) {
                int row = kg * 4 + r + 16 * rf;
                f32x4 v;
#pragma unroll
                for (int q = 0; q < 4; ++q) v[q] = acc[rf][q][r];
                *(f32x4*)&lds[wv][row][4 * cq] = v;
            }
        __syncthreads();
        int row = tid >> 3, c0 = (tid & 7) * 8;
        int gcol = chunk * 64 + c0;
        f32x4 o0, o1;
#pragma unroll
        for (int j = 0; j < 4; ++j) {
            o0[j] = lds[0][row][c0 + j] + lds[1][row][c0 + j]
                  + lds[2][row][c0 + j] + lds[3][row][c0 + j]
                  + ae_b3[c * EMB + gcol + j];
            o1[j] = lds[0][row][c0 + 4 + j] + lds[1][row][c0 + 4 + j]
                  + lds[2][row][c0 + 4 + j] + lds[3][row][c0 + 4 + j]
                  + ae_b3[c * EMB + gcol + 4 + j];
        }
        float* orow = out + ((size_t)b * 33 + 1 + row) * EMB + gcol;
        *(f32x4*)orow = o0;
        *(f32x4*)(orow + 4) = o1;
    }
}

// ---------------------------------------------------------------------------
// workspace layout (bytes):
//   0      : gate_ae int[32], gate_h int[32], gate_x3 int[32]  (384, memset 0)
//   512    : tau     bf16[32][1536]     (98304)
//   98816  : h       f32 [32][1024]     (131072)
//   229888 : a_emb   bf16[32][32][1536] (3145728)
//   3375616: x3      bf16[32][32][1536] (3145728)
//   total  : 6521344
// ---------------------------------------------------------------------------
extern "C" void kernel_launch(void* const* d_in, const int* in_sizes, int n_in,
                              void* d_out, int out_size, void* d_ws, size_t ws_size,
                              hipStream_t stream) {
    const float* state   = (const float*)d_in[0];
    const float* actions = (const float*)d_in[1];
    const int*   tsteps  = (const int*)d_in[2];
    const int*   cat_ids = (const int*)d_in[3];
    const float* se_W1 = (const float*)d_in[4];
    const float* se_b1 = (const float*)d_in[5];
    const float* se_W2 = (const float*)d_in[6];
    const float* se_b2 = (const float*)d_in[7];
    const float* ae_W1 = (const float*)d_in[8];
    const float* ae_b1 = (const float*)d_in[9];
    const float* ae_W2 = (const float*)d_in[10];
    const float* ae_b2 = (const float*)d_in[11];
    const float* ae_W3 = (const float*)d_in[12];
    const float* ae_b3 = (const float*)d_in[13];
    float* out = (float*)d_out;

    char* ws = (char*)d_ws;
    int*            gate_ae = (int*)(ws + 0);
    int*            gate_h  = (int*)(ws + 128);
    int*            gate_x3 = (int*)(ws + 256);
    unsigned short* tau     = (unsigned short*)(ws + 512);
    float*          h       = (float*)(ws + 98816);
    unsigned short* aemb    = (unsigned short*)(ws + 229888);
    unsigned short* x3      = (unsigned short*)(ws + 3375616);

    hipMemsetAsync(ws, 0, 384, stream);
    k_fused<<<NBLK, 256, 0, stream>>>(
        state, actions, tsteps, cat_ids,
        se_W1, se_b1, se_W2, se_b2,
        ae_W1, ae_b1, ae_W2, ae_b2, ae_W3, ae_b3,
        gate_ae, gate_h, gate_x3, tau, h, aemb, x3, out);
}

// Round 5
// 265.351 us; speedup vs baseline: 1.1982x; 1.1982x over previous
//
#include <hip/hip_runtime.h>
#include <hip/hip_bf16.h>

#define B_   32
#define T_   32
#define E_   32
#define SD   64
#define AD   32
#define HID  1024
#define EMB  1536
#define K2   3072   // 2*EMB

// block ranges within the fused kernel (producers strictly before consumers)
#define NB_AE   (6 * B_)                 // 192  (aemb chunks; chunk0 also tau)
#define NB_SH   B_                       // 32   (state_h)
#define NB_SF   ((EMB / 256) * B_)       // 192  (state_feat)
#define NB_B1   ((EMB / 64) * B_)        // 768  (big GEMM 1)
#define NB_K2   ((EMB / 64) * B_)        // 768  (big GEMM 2)
#define OFF_SH  NB_AE                    // 192
#define OFF_SF  (OFF_SH + NB_SH)         // 224
#define OFF_B1  (OFF_SF + NB_SF)         // 416
#define OFF_K2  (OFF_B1 + NB_B1)         // 1184
#define NBLK    (OFF_K2 + NB_K2)         // 1952

typedef __attribute__((ext_vector_type(8))) short  bf16x8;
typedef __attribute__((ext_vector_type(8))) short  s16x8;
typedef __attribute__((ext_vector_type(4))) float  f32x4;

// round-to-nearest-even f32 -> bf16 bits
__device__ __forceinline__ unsigned short f2bf(float f) {
    unsigned u = __builtin_bit_cast(unsigned, f);
    u = u + 0x7fffu + ((u >> 16) & 1u);
    return (unsigned short)(u >> 16);
}

__device__ __forceinline__ float swishf(float y) {
    return y / (1.f + expf(-y));
}

// producer: all threads done storing -> __syncthreads() -> tid0 signals once
__device__ __forceinline__ void gate_signal(int* g) {
    __syncthreads();
    if (threadIdx.x == 0)
        __hip_atomic_fetch_add(g, 1, __ATOMIC_RELEASE, __HIP_MEMORY_SCOPE_AGENT);
}

// consumer: RELAXED spin (no per-iteration cache invalidation!), then a
// single agent-scope acquire fence once the gate opens.
__device__ __forceinline__ void gate_wait(const int* g, int target) {
    if (threadIdx.x == 0) {
        while (__hip_atomic_load(g, __ATOMIC_RELAXED, __HIP_MEMORY_SCOPE_AGENT) < target)
            __builtin_amdgcn_s_sleep(8);
        __builtin_amdgcn_fence(__ATOMIC_ACQUIRE, "agent");
    }
    __syncthreads();
}

// per-block cat-sort: threads 0..31 rank their batch, scratch[rank]=b.
// Contains a __syncthreads(); caller must barrier again before overwriting
// scratch (gate_wait provides it).
__device__ __forceinline__ int sorted_b(const int* __restrict__ cat_ids,
                                        int slot, int* scratch) {
    int tid = threadIdx.x;
    if (tid < B_) {
        int myc = cat_ids[tid];
        int rank = 0;
        for (int j = 0; j < B_; ++j) {
            int cj = cat_ids[j];
            rank += (cj < myc) || (cj == myc && j < tid);
        }
        scratch[rank] = tid;
    }
    __syncthreads();
    return scratch[slot];
}

// ---------------------------------------------------------------------------
// fused kernel: prep (aemb+tau, state_h) -> state_feat + big1 -> big2,
// gated per-batch; consumers spin relaxed so streams keep their caches.
// ---------------------------------------------------------------------------
__global__ __launch_bounds__(256) void k_fused(
    const float* __restrict__ state, const float* __restrict__ actions,
    const int* __restrict__ tsteps, const int* __restrict__ cat_ids,
    const float* __restrict__ se_W1, const float* __restrict__ se_b1,
    const float* __restrict__ se_W2, const float* __restrict__ se_b2,
    const float* __restrict__ ae_W1, const float* __restrict__ ae_b1,
    const float* __restrict__ ae_W2, const float* __restrict__ ae_b2,
    const float* __restrict__ ae_W3, const float* __restrict__ ae_b3,
    int* __restrict__ gate_ae, int* __restrict__ gate_h, int* __restrict__ gate_x3,
    unsigned short* __restrict__ tau, float* __restrict__ h,
    unsigned short* __restrict__ aemb, unsigned short* __restrict__ x3,
    float* __restrict__ out) {
    __shared__ float lds[4][32][64];        // 32 KB, reused by all branches
    int bid = blockIdx.x, tid = threadIdx.x;
    int wv = tid >> 6, lane = tid & 63;

    if (bid < NB_AE) {
        // ---- aemb (b-major): b's 6 chunks adjacent; chunk 0 also does tau
        int b = bid / 6, chunk = bid % 6;
        int c = cat_ids[b];
        if (chunk == 0) {
            float t = (float)tsteps[b];
            const int half = EMB / 2;
            for (int i = tid; i < half; i += 256) {
                float div = expf((-logf(10000.0f) * (float)i) / (float)half);
                float ang = t * div;
                tau[b * EMB + i]        = f2bf(sinf(ang));
                tau[b * EMB + half + i] = f2bf(cosf(ang));
            }
        }
        float* sa = (float*)lds;
#pragma unroll
        for (int r = 0; r < 4; ++r)
            sa[tid + 256 * r] = actions[b * T_ * AD + tid + 256 * r];
        __syncthreads();
        int n = chunk * 256 + tid;
        const float* W = ae_W1 + (size_t)c * AD * EMB + n;
        float bv = ae_b1[c * EMB + n];
        float acc[T_];
#pragma unroll
        for (int t = 0; t < T_; ++t) acc[t] = bv;
        for (int k = 0; k < AD; ++k) {
            float w = W[(size_t)k * EMB];
#pragma unroll
            for (int t = 0; t < T_; ++t) acc[t] += sa[t * AD + k] * w;
        }
#pragma unroll
        for (int t = 0; t < T_; ++t)
            aemb[((size_t)b * T_ + t) * EMB + n] = f2bf(acc[t]);
        gate_signal(&gate_ae[b]);
        return;
    }

    if (bid < OFF_SF) {
        // ---- state_h: h = relu(state @ se_W1 + se_b1)
        int b = bid - OFF_SH;
        int c = cat_ids[b];
        float* s = (float*)lds;
        if (tid < SD) s[tid] = state[b * SD + tid];
        __syncthreads();
        const float* W = se_W1 + (size_t)c * SD * HID;
        float acc[4];
#pragma unroll
        for (int r = 0; r < 4; ++r) acc[r] = se_b1[c * HID + tid + 256 * r];
        for (int k = 0; k < SD; ++k) {
            float sv = s[k];
#pragma unroll
            for (int r = 0; r < 4; ++r)
                acc[r] += sv * W[(size_t)k * HID + tid + 256 * r];
        }
#pragma unroll
        for (int r = 0; r < 4; ++r) {
            float v = acc[r];
            h[b * HID + tid + 256 * r] = v > 0.f ? v : 0.f;
        }
        gate_signal(&gate_h[b]);
        return;
    }

    if (bid < OFF_B1) {
        // ---- state_feat: out[b,0,:] = h @ se_W2 + se_b2 (overlaps big1)
        int idx = bid - OFF_SF;
        int slot = idx & 31, chunk = idx >> 5;
        int b = sorted_b(cat_ids, slot, (int*)lds);
        int c = cat_ids[b];
        gate_wait(&gate_h[b], 1);
        int n = chunk * 256 + 4 * lane;
        const float* W = se_W2 + (size_t)c * HID * EMB + n;
        const float* hb = h + (size_t)b * HID;
        f32x4 acc = {0.f, 0.f, 0.f, 0.f};
        int ke = 256 * wv + 256;
#pragma unroll 16
        for (int k = 256 * wv; k < ke; ++k) {
            f32x4 wvv = *(const f32x4*)(W + (size_t)k * EMB);
            float hk = hb[k];
            acc += hk * wvv;
        }
        __syncthreads();                    // lds: order scratch -> reduce buf
        float* l = (float*)lds;
        *(f32x4*)&l[(wv * 64 + lane) * 4] = acc;
        __syncthreads();
        if (tid < 64) {
            f32x4 s = *(f32x4*)&l[tid * 4];
#pragma unroll
            for (int w = 1; w < 4; ++w) s += *(f32x4*)&l[(w * 64 + tid) * 4];
            s += *(const f32x4*)(se_b2 + (size_t)c * EMB + chunk * 256 + 4 * tid);
            *(f32x4*)(out + ((size_t)b * 33) * EMB + chunk * 256 + 4 * tid) = s;
        }
        return;
    }

    if (bid < OFF_K2) {
        // ---- big1: x3 = swish(concat(a_emb,tau) @ ae_W2 + ae_b2), bf16 out
        // sorted-batch-major: 24 chunk-blocks per batch adjacent, batches in
        // cat order (same-cat batches stream the same weights concurrently).
        int idx = bid - OFF_B1;
        int slot = idx / 24, chunk = idx % 24;
        int b = sorted_b(cat_ids, slot, (int*)lds);
        int c = cat_ids[b];
        int cq = lane & 15, kg = lane >> 4;
        int ncol = chunk * 64 + 4 * cq;
        const float* Wb = ae_W2 + (size_t)c * K2 * EMB + ncol;

        gate_wait(&gate_ae[b], 6);

        f32x4 acc[2][4];
#pragma unroll
        for (int rf = 0; rf < 2; ++rf)
#pragma unroll
            for (int q = 0; q < 4; ++q) acc[rf][q] = (f32x4){0.f, 0.f, 0.f, 0.f};

        int kbeg = wv * 768;
        if (wv < 2) {                       // a_emb region (k 0..1535)
            const unsigned short* A0 = aemb + (size_t)b * T_ * EMB;
#pragma unroll 2
            for (int kk = 0; kk < 768; kk += 32) {
                int kb = kbeg + kk + kg * 8;
                f32x4 w[8];
#pragma unroll
                for (int j = 0; j < 8; ++j)
                    w[j] = *(const f32x4*)(Wb + (size_t)(kb + j) * EMB);
                bf16x8 bq[4];
#pragma unroll
                for (int q = 0; q < 4; ++q)
#pragma unroll
                    for (int j = 0; j < 8; ++j) bq[q][j] = (short)f2bf(w[j][q]);
                bf16x8 a0 = *(const bf16x8*)(A0 + (size_t)cq * EMB + kb);
                bf16x8 a1 = *(const bf16x8*)(A0 + (size_t)(cq + 16) * EMB + kb);
#pragma unroll
                for (int q = 0; q < 4; ++q) {
                    acc[0][q] = __builtin_amdgcn_mfma_f32_16x16x32_bf16(a0, bq[q], acc[0][q], 0, 0, 0);
                    acc[1][q] = __builtin_amdgcn_mfma_f32_16x16x32_bf16(a1, bq[q], acc[1][q], 0, 0, 0);
                }
            }
        } else {                            // tau region (k 1536..3071)
            const unsigned short* TA = tau + (size_t)b * EMB;
#pragma unroll 2
            for (int kk = 0; kk < 768; kk += 32) {
                int kb = kbeg + kk + kg * 8;
                f32x4 w[8];
#pragma unroll
                for (int j = 0; j < 8; ++j)
                    w[j] = *(const f32x4*)(Wb + (size_t)(kb + j) * EMB);
                bf16x8 bq[4];
#pragma unroll
                for (int q = 0; q < 4; ++q)
#pragma unroll
                    for (int j = 0; j < 8; ++j) bq[q][j] = (short)f2bf(w[j][q]);
                bf16x8 a = *(const bf16x8*)(TA + (kb - EMB));
#pragma unroll
                for (int q = 0; q < 4; ++q) {
                    acc[0][q] = __builtin_amdgcn_mfma_f32_16x16x32_bf16(a, bq[q], acc[0][q], 0, 0, 0);
                    acc[1][q] = __builtin_amdgcn_mfma_f32_16x16x32_bf16(a, bq[q], acc[1][q], 0, 0, 0);
                }
            }
        }
#pragma unroll
        for (int rf = 0; rf < 2; ++rf)
#pragma unroll
            for (int r = 0; r < 4; ++r) {
                int row = kg * 4 + r + 16 * rf;
                f32x4 v;
#pragma unroll
                for (int q = 0; q < 4; ++q) v[q] = acc[rf][q][r];
                *(f32x4*)&lds[wv][row][4 * cq] = v;
            }
        __syncthreads();
        int row = tid >> 3, c0 = (tid & 7) * 8;
        int gcol = chunk * 64 + c0;
        s16x8 o;
#pragma unroll
        for (int j = 0; j < 8; ++j) {
            float y = lds[0][row][c0 + j] + lds[1][row][c0 + j]
                    + lds[2][row][c0 + j] + lds[3][row][c0 + j]
                    + ae_b2[c * EMB + gcol + j];
            o[j] = (short)f2bf(swishf(y));
        }
        *(s16x8*)(x3 + ((size_t)b * T_ + row) * EMB + gcol) = o;
        gate_signal(&gate_x3[b]);
        return;
    }

    {
        // ---- big2: out[b,1+t,:] = x3 @ ae_W3 + ae_b3 (backfills big1 tail)
        int idx = bid - OFF_K2;
        int slot = idx / 24, chunk = idx % 24;
        int b = sorted_b(cat_ids, slot, (int*)lds);
        int c = cat_ids[b];
        int cq = lane & 15, kg = lane >> 4;
        int ncol = chunk * 64 + 4 * cq;
        const float* Wb = ae_W3 + (size_t)c * EMB * EMB + ncol;

        gate_wait(&gate_x3[b], 24);
        const unsigned short* A0 = x3 + (size_t)b * T_ * EMB;

        f32x4 acc[2][4];
#pragma unroll
        for (int rf = 0; rf < 2; ++rf)
#pragma unroll
            for (int q = 0; q < 4; ++q) acc[rf][q] = (f32x4){0.f, 0.f, 0.f, 0.f};

        int kbeg = wv * 384;
#pragma unroll 2
        for (int kk = 0; kk < 384; kk += 32) {
            int kb = kbeg + kk + kg * 8;
            f32x4 w[8];
#pragma unroll
            for (int j = 0; j < 8; ++j)
                w[j] = *(const f32x4*)(Wb + (size_t)(kb + j) * EMB);
            bf16x8 bq[4];
#pragma unroll
            for (int q = 0; q < 4; ++q)
#pragma unroll
                for (int j = 0; j < 8; ++j) bq[q][j] = (short)f2bf(w[j][q]);
            bf16x8 a0 = *(const bf16x8*)(A0 + (size_t)cq * EMB + kb);
            bf16x8 a1 = *(const bf16x8*)(A0 + (size_t)(cq + 16) * EMB + kb);
#pragma unroll
            for (int q = 0; q < 4; ++q) {
                acc[0][q] = __builtin_amdgcn_mfma_f32_16x16x32_bf16(a0, bq[q], acc[0][q], 0, 0, 0);
                acc[1][q] = __builtin_amdgcn_mfma_f32_16x16x32_bf16(a1, bq[q], acc[1][q], 0, 0, 0);
            }
        }
#pragma unroll
        for (int rf = 0; rf < 2; ++rf)
#pragma unroll
            for (int r = 0; r < 4; ++r) {
                int row = kg * 4 + r + 16 * rf;
                f32x4 v;
#pragma unroll
                for (int q = 0; q < 4; ++q) v[q] = acc[rf][q][r];
                *(f32x4*)&lds[wv][row][4 * cq] = v;
            }
        __syncthreads();
        int row = tid >> 3, c0 = (tid & 7) * 8;
        int gcol = chunk * 64 + c0;
        f32x4 o0, o1;
#pragma unroll
        for (int j = 0; j < 4; ++j) {
            o0[j] = lds[0][row][c0 + j] + lds[1][row][c0 + j]
                  + lds[2][row][c0 + j] + lds[3][row][c0 + j]
                  + ae_b3[c * EMB + gcol + j];
            o1[j] = lds[0][row][c0 + 4 + j] + lds[1][row][c0 + 4 + j]
                  + lds[2][row][c0 + 4 + j] + lds[3][row][c0 + 4 + j]
                  + ae_b3[c * EMB + gcol + 4 + j];
        }
        float* orow = out + ((size_t)b * 33 + 1 + row) * EMB + gcol;
        *(f32x4*)orow = o0;
        *(f32x4*)(orow + 4) = o1;
    }
}

// ---------------------------------------------------------------------------
// workspace layout (bytes):
//   0      : gate_ae int[32], gate_h int[32], gate_x3 int[32]  (384, memset 0)
//   512    : tau     bf16[32][1536]     (98304)
//   98816  : h       f32 [32][1024]     (131072)
//   229888 : a_emb   bf16[32][32][1536] (3145728)
//   3375616: x3      bf16[32][32][1536] (3145728)
//   total  : 6521344
// ---------------------------------------------------------------------------
extern "C" void kernel_launch(void* const* d_in, const int* in_sizes, int n_in,
                              void* d_out, int out_size, void* d_ws, size_t ws_size,
                              hipStream_t stream) {
    const float* state   = (const float*)d_in[0];
    const float* actions = (const float*)d_in[1];
    const int*   tsteps  = (const int*)d_in[2];
    const int*   cat_ids = (const int*)d_in[3];
    const float* se_W1 = (const float*)d_in[4];
    const float* se_b1 = (const float*)d_in[5];
    const float* se_W2 = (const float*)d_in[6];
    const float* se_b2 = (const float*)d_in[7];
    const float* ae_W1 = (const float*)d_in[8];
    const float* ae_b1 = (const float*)d_in[9];
    const float* ae_W2 = (const float*)d_in[10];
    const float* ae_b2 = (const float*)d_in[11];
    const float* ae_W3 = (const float*)d_in[12];
    const float* ae_b3 = (const float*)d_in[13];
    float* out = (float*)d_out;

    char* ws = (char*)d_ws;
    int*            gate_ae = (int*)(ws + 0);
    int*            gate_h  = (int*)(ws + 128);
    int*            gate_x3 = (int*)(ws + 256);
    unsigned short* tau     = (unsigned short*)(ws + 512);
    float*          h       = (float*)(ws + 98816);
    unsigned short* aemb    = (unsigned short*)(ws + 229888);
    unsigned short* x3      = (unsigned short*)(ws + 3375616);

    hipMemsetAsync(ws, 0, 384, stream);
    k_fused<<<NBLK, 256, 0, stream>>>(
        state, actions, tsteps, cat_ids,
        se_W1, se_b1, se_W2, se_b2,
        ae_W1, ae_b1, ae_W2, ae_b2, ae_W3, ae_b3,
        gate_ae, gate_h, gate_x3, tau, h, aemb, x3, out);
}